// Round 3
// baseline (545.382 us; speedup 1.0000x reference)
//
#include <hip/hip_runtime.h>
#include <hip/hip_bf16.h>

static constexpr int Bc = 4, Nc = 512, Cc = 128, EDc = 64, ED2c = 128, ATTc = 8, INc = 128;
static constexpr int Mc = Nc - 1; // 511

// workspace layout (floats) — 198,656 floats = 794,624 bytes (fits; R2 showed no fault at this size)
static constexpr int OFF_WCOMB = 0;                        // 4*128*128 = 65536
static constexpr int OFF_BCOMB = OFF_WCOMB + Bc*ED2c*Cc;   // +512
static constexpr int OFF_H     = OFF_BCOMB + Bc*ED2c;      // +131072 (4*512*64 fp32)
static constexpr int OFF_MAX   = OFF_H + Bc*Nc*EDc;        // +512
static constexpr int OFF_DEN   = OFF_MAX + Bc*INc;         // +512
static constexpr int OFF_ACC   = OFF_DEN + Bc*INc;         // +512
// end = 198,656 floats

// output layout (fp32): node_out[512] | tmp_p[4*128*511] | et_p[4*128*511]
static constexpr int OUT_TMP = Bc*INc;                     // 512
static constexpr int OUT_ETP = OUT_TMP + Bc*INc*Mc;        // 512 + 261632

__device__ __forceinline__ float gelu_f(float x){ return 0.5f*x*(1.0f + erff(x*0.70710678118654752f)); }
__device__ __forceinline__ float rho_f(float x){ return copysignf(sqrtf(fabsf(x)), x); }

// K1: per-batch q = node[b,0]@Wq^T + b, then Wcomb[e,c] = sum_a q[a,e]*Wk_w[a*128+e,c]
__global__ void k1_qcomb(const float* __restrict__ node,
                         const float* __restrict__ Wq_w, const float* __restrict__ Wq_b,
                         const float* __restrict__ Wk_w, const float* __restrict__ Wk_b,
                         float* __restrict__ ws){
    int b = blockIdx.x;
    int t = threadIdx.x; // 256
    __shared__ float node0[Cc];
    __shared__ float q[ATTc*ED2c]; // 1024
    if (t < Cc) node0[t] = node[(b*Nc + 0)*Cc + t];
    __syncthreads();
    for (int row = t; row < ATTc*ED2c; row += 256){
        float acc = Wq_b[row];
        const float* wr = Wq_w + row*Cc;
        #pragma unroll 8
        for (int c = 0; c < Cc; ++c) acc += node0[c]*wr[c];
        q[row] = acc;
    }
    __syncthreads();
    float* Wcomb = ws + OFF_WCOMB + b*ED2c*Cc;
    for (int idx = t; idx < ED2c*Cc; idx += 256){
        int e = idx >> 7, c = idx & 127;
        float acc = 0.f;
        #pragma unroll
        for (int a = 0; a < ATTc; ++a)
            acc += q[a*ED2c + e] * Wk_w[(a*ED2c + e)*Cc + c];
        Wcomb[idx] = acc;
    }
    if (t < ED2c){
        float acc = 0.f;
        #pragma unroll
        for (int a = 0; a < ATTc; ++a) acc += q[a*ED2c + t]*Wk_b[a*ED2c + t];
        ws[OFF_BCOMB + b*ED2c + t] = acc;
    }
    if (t < INc) ws[OFF_ACC + b*INc + t] = 0.f; // zero node_out accumulator
}

// K2: per (b,n): qk -> h (stored fp32 to ws)
__global__ void k2_h(const float* __restrict__ node,
                     const float* __restrict__ edge, const float* __restrict__ emb,
                     const float* __restrict__ Wew, const float* __restrict__ Web,
                     float* __restrict__ ws){
    int bn = blockIdx.x;
    int b = bn >> 9, n = bn & 511;
    int t = threadIdx.x; // 0..127
    __shared__ float nrow[Cc], e0[EDc], em[EDc], qk[ED2c], ew[EDc], eb[EDc];
    nrow[t] = node[(b*Nc + n)*Cc + t];
    size_t eoff = ((size_t)b*Nc*Nc + n)*EDc;
    if (t < EDc) e0[t]     = edge[eoff + t];
    else         em[t-EDc] = emb[eoff + (t-EDc)];
    __syncthreads();
    // qk[t] = node . Wcomb[b,t,:] + bcomb[b,t]
    {
        const float* Wc = ws + OFF_WCOMB + b*ED2c*Cc + t*Cc;
        float acc = ws[OFF_BCOMB + b*ED2c + t];
        #pragma unroll 8
        for (int c = 0; c < Cc; ++c) acc += nrow[c]*Wc[c];
        qk[t] = acc;
    }
    float dotv = 0.f;
    if (t < EDc){
        const float* w = Wew + t*EDc;
        #pragma unroll 8
        for (int c = 0; c < EDc; ++c) dotv += e0[c]*w[c];
        ew[t] = dotv;
    } else {
        int d = t - EDc;
        const float* w = Web + d*EDc;
        #pragma unroll 8
        for (int c = 0; c < EDc; ++c) dotv += e0[c]*w[c];
        eb[d] = dotv;
    }
    __syncthreads();
    if (t < EDc){
        float x = rho_f(qk[t]*ew[t]) + eb[t] + qk[EDc + t] + em[t];
        ws[OFF_H + (b*Nc + n)*EDc + t] = gelu_f(x);
    }
}

// K3: per (b,j): recompute s[m] = h[b,m+1] . Wa[j] on the fly; softmax stats over m.
__global__ void k3_stats(const float* __restrict__ Wa, float* __restrict__ ws){
    int bj = blockIdx.x;      // b*128 + j
    int b = bj >> 7, j = bj & 127;
    int l = threadIdx.x;      // 0..63
    __shared__ float wa[EDc];
    if (l < EDc) wa[l] = Wa[j*EDc + l];
    __syncthreads();
    float sv[8];
    float mx = -1e30f;
    #pragma unroll
    for (int i = 0; i < 8; ++i){
        int m = l + i*64;
        float s = -1e30f;
        if (m < Mc){
            const float* hp = ws + OFF_H + (b*Nc + m + 1)*EDc;
            s = 0.f;
            #pragma unroll 8
            for (int d = 0; d < EDc; ++d) s += hp[d]*wa[d];
        }
        sv[i] = s;
        mx = fmaxf(mx, s);
    }
    #pragma unroll
    for (int off = 32; off > 0; off >>= 1) mx = fmaxf(mx, __shfl_xor(mx, off));
    float sum = 0.f;
    #pragma unroll
    for (int i = 0; i < 8; ++i) if (sv[i] > -1e29f) sum += expf(sv[i] - mx);
    #pragma unroll
    for (int off = 32; off > 0; off >>= 1) sum += __shfl_xor(sum, off);
    if (l == 0){ ws[OFF_MAX + bj] = mx; ws[OFF_DEN + bj] = 1.0f/sum; }
}

// K4: 8 m-rows per block: s (recomputed), alpha, et, nt, h1-gelu, h2, outputs
__global__ void __launch_bounds__(128) k4_mlp(const float* __restrict__ node,
                       const float* __restrict__ Wa,
                       const float* __restrict__ et_w, const float* __restrict__ et_b,
                       const float* __restrict__ nt_w, const float* __restrict__ nt_b,
                       const float* __restrict__ h1_w, const float* __restrict__ h1_b,
                       const float* __restrict__ h2_w, const float* __restrict__ h2_b,
                       float* __restrict__ ws, float* __restrict__ out){
    constexpr int TM = 8;
    int blk = blockIdx.x;
    int b = blk >> 6;
    int m0 = (blk & 63)*TM;
    int t = threadIdx.x;               // j
    int nm = Mc - m0; if (nm > TM) nm = TM;
    __shared__ float esh[TM][EDc];
    __shared__ float nsh[TM][Cc];
    __shared__ float cat[TM][2*INc];
    __shared__ float gsh[TM][INc];
    for (int i = t; i < TM*EDc; i += 128){
        int mi = i >> 6, d = i & 63;
        int row = m0 + mi + 1; if (row > Nc-1) row = Nc-1;
        esh[mi][d] = ws[OFF_H + (b*Nc + row)*EDc + d];
    }
    for (int i = t; i < TM*Cc; i += 128){
        int mi = i >> 7, c = i & 127;
        int row = m0 + mi + 1; if (row > Nc-1) row = Nc-1;
        nsh[mi][c] = node[(b*Nc + row)*Cc + c];
    }
    __syncthreads();
    float mx  = ws[OFF_MAX + b*INc + t];
    float inv = ws[OFF_DEN + b*INc + t];
    float acc[TM];
    float alpha[TM];
    // recompute s[mi] = esh[mi] . Wa[t] -> alpha
    {
        #pragma unroll
        for (int mi = 0; mi < TM; ++mi) acc[mi] = 0.f;
        const float* w = Wa + t*EDc;
        for (int d = 0; d < EDc; ++d){
            float wv = w[d];
            #pragma unroll
            for (int mi = 0; mi < TM; ++mi) acc[mi] += esh[mi][d]*wv;
        }
        #pragma unroll
        for (int mi = 0; mi < TM; ++mi) alpha[mi] = expf(acc[mi] - mx)*inv;
    }
    // et
    {
        float bb = et_b[t];
        #pragma unroll
        for (int mi = 0; mi < TM; ++mi) acc[mi] = 0.f;
        const float* w = et_w + t*EDc;
        for (int c = 0; c < EDc; ++c){
            float wv = w[c];
            #pragma unroll
            for (int mi = 0; mi < TM; ++mi) acc[mi] += esh[mi][c]*wv;
        }
        #pragma unroll
        for (int mi = 0; mi < TM; ++mi){
            float v = (acc[mi] + bb)*alpha[mi];
            cat[mi][t] = v;
            if (mi < nm) out[OUT_ETP + (b*INc + t)*Mc + (m0 + mi)] = v;
        }
    }
    // nt
    {
        float bb = nt_b[t];
        #pragma unroll
        for (int mi = 0; mi < TM; ++mi) acc[mi] = 0.f;
        const float* w = nt_w + t*Cc;
        for (int c = 0; c < Cc; ++c){
            float wv = w[c];
            #pragma unroll
            for (int mi = 0; mi < TM; ++mi) acc[mi] += nsh[mi][c]*wv;
        }
        #pragma unroll
        for (int mi = 0; mi < TM; ++mi) cat[mi][INc + t] = (acc[mi] + bb)*alpha[mi];
    }
    __syncthreads();
    // h1 + gelu
    {
        float bb = h1_b[t];
        #pragma unroll
        for (int mi = 0; mi < TM; ++mi) acc[mi] = 0.f;
        const float* w = h1_w + t*(2*INc);
        for (int c = 0; c < 2*INc; ++c){
            float wv = w[c];
            #pragma unroll
            for (int mi = 0; mi < TM; ++mi) acc[mi] += cat[mi][c]*wv;
        }
        #pragma unroll
        for (int mi = 0; mi < TM; ++mi) gsh[mi][t] = gelu_f(acc[mi] + bb);
    }
    __syncthreads();
    // h2 + outputs
    {
        float bb = h2_b[t];
        #pragma unroll
        for (int mi = 0; mi < TM; ++mi) acc[mi] = 0.f;
        const float* w = h2_w + t*INc;
        for (int c = 0; c < INc; ++c){
            float wv = w[c];
            #pragma unroll
            for (int mi = 0; mi < TM; ++mi) acc[mi] += gsh[mi][c]*wv;
        }
        float lsum = 0.f;
        #pragma unroll
        for (int mi = 0; mi < TM; ++mi){
            if (mi < nm){
                float v = acc[mi] + bb;
                out[OUT_TMP + (b*INc + t)*Mc + (m0 + mi)] = v;
                lsum += v;
            }
        }
        atomicAdd(&ws[OFF_ACC + b*INc + t], lsum);
    }
}

// K5: node_out = acc * 2/sqrt(C)
__global__ void k5_nodeout(const float* __restrict__ ws, float* __restrict__ out){
    int i = blockIdx.x*256 + threadIdx.x;
    if (i < Bc*INc) out[i] = ws[OFF_ACC + i]*0.17677669529663687f;
}

extern "C" void kernel_launch(void* const* d_in, const int* in_sizes, int n_in,
                              void* d_out, int out_size, void* d_ws, size_t ws_size,
                              hipStream_t stream){
    const float* node = (const float*)d_in[0];
    const float* edge = (const float*)d_in[1];
    const float* emb  = (const float*)d_in[2];
    const float* Wq_w = (const float*)d_in[3];
    const float* Wq_b = (const float*)d_in[4];
    const float* Wk_w = (const float*)d_in[5];
    const float* Wk_b = (const float*)d_in[6];
    const float* Wew  = (const float*)d_in[7];
    const float* Web  = (const float*)d_in[8];
    const float* Wa   = (const float*)d_in[9];
    const float* nt_w = (const float*)d_in[10];
    const float* nt_b = (const float*)d_in[11];
    const float* et_w = (const float*)d_in[12];
    const float* et_b = (const float*)d_in[13];
    const float* h1_w = (const float*)d_in[14];
    const float* h1_b = (const float*)d_in[15];
    const float* h2_w = (const float*)d_in[16];
    const float* h2_b = (const float*)d_in[17];
    float* ws = (float*)d_ws;
    float* out = (float*)d_out;

    k1_qcomb<<<Bc, 256, 0, stream>>>(node, Wq_w, Wq_b, Wk_w, Wk_b, ws);
    k2_h<<<Bc*Nc, 128, 0, stream>>>(node, edge, emb, Wew, Web, ws);
    k3_stats<<<Bc*INc, 64, 0, stream>>>(Wa, ws);
    k4_mlp<<<Bc*64, 128, 0, stream>>>(node, Wa, et_w, et_b, nt_w, nt_b,
                                      h1_w, h1_b, h2_w, h2_b, ws, out);
    k5_nodeout<<<2, 256, 0, stream>>>(ws, out);
}